// Round 1
// baseline (620.276 us; speedup 1.0000x reference)
//
#include <hip/hip_runtime.h>
#include <hip/hip_bf16.h>
#include <stdint.h>

#define IN_F 4096
#define OUT_F 4096
#define BM 128
#define BN 128
#define BK 32

typedef __attribute__((ext_vector_type(8))) __bf16 bf16x8;
typedef __attribute__((ext_vector_type(4))) __bf16 bf16x4;
typedef __attribute__((ext_vector_type(4))) float f32x4;

__device__ __forceinline__ void gl_lds_16(const void* g, void* l) {
    __builtin_amdgcn_global_load_lds((const __attribute__((address_space(1))) void*)g,
                                     (__attribute__((address_space(3))) void*)l,
                                     16, 0, 0);
}

// ---- zero fp32 W ----
__global__ void zero_f4(float4* __restrict__ p, int n4) {
    int i = blockIdx.x * blockDim.x + threadIdx.x;
    if (i < n4) p[i] = make_float4(0.f, 0.f, 0.f, 0.f);
}

// ---- COO scatter-add: W flat layout [out*4096+in] == flat_idx directly ----
__global__ void scatter_add(const float* __restrict__ vals, const int* __restrict__ idx,
                            float* __restrict__ W, int nnz) {
    int i = blockIdx.x * blockDim.x + threadIdx.x;
    if (i < nnz) atomicAdd(&W[idx[i]], vals[i]);
}

// ---- fp32 -> bf16, 4 elems/thread ----
__global__ void cvt_f32_bf16(const float* __restrict__ in, __bf16* __restrict__ out, int n4) {
    int i = blockIdx.x * blockDim.x + threadIdx.x;
    if (i < n4) {
        float4 v = *(const float4*)(in + (size_t)i * 4);
        bf16x4 o;
        o[0] = (__bf16)v.x; o[1] = (__bf16)v.y; o[2] = (__bf16)v.z; o[3] = (__bf16)v.w;
        *(bf16x4*)(out + (size_t)i * 4) = o;
    }
}

// ---- GEMM: C[M,N] = A[M,K] * B[N,K]^T + bias,  bf16 in / fp32 out ----
// m97 structure: 128x128 tile, BK=32, 4 waves 2x2, global_load_lds width=16.
__global__ __launch_bounds__(256) void gemm_bf16_bt(
    const __bf16* __restrict__ A, const __bf16* __restrict__ B,
    const float* __restrict__ bias, float* __restrict__ C,
    int M, int N, int K)
{
    __shared__ __align__(16) __bf16 sA[BM * BK];  // 8 KB, unpadded row-major (global_load_lds needs it)
    __shared__ __align__(16) __bf16 sB[BN * BK];  // 8 KB

    const int t = threadIdx.x;
    const int wave = t >> 6;
    const int lane = t & 63;
    const int wm = wave >> 1;      // 0..1 — wave row in 2x2
    const int wn = wave & 1;       // 0..1 — wave col
    const int lq = lane >> 4;      // quad 0..3
    const int lr = lane & 15;      // row-in-16-tile

    const int tileM = blockIdx.y * BM;
    const int tileN = blockIdx.x * BN;

    // staging: per issue, 256 threads x 16B = 64 rows of 32 bf16; 2 issues cover 128 rows
    const int srow = wave * 16 + (lane >> 2);   // 0..63
    const int scol = (lane & 3) * 8;            // 0,8,16,24

    const __bf16* gA0 = A + (size_t)(tileM + srow) * K + scol;
    const __bf16* gA1 = A + (size_t)(tileM + 64 + srow) * K + scol;
    const __bf16* gB0 = B + (size_t)(tileN + srow) * K + scol;
    const __bf16* gB1 = B + (size_t)(tileN + 64 + srow) * K + scol;
    __bf16* lA0 = &sA[srow * BK + scol];        // == waveBase + lane*16B  (DMA layout constraint)
    __bf16* lA1 = &sA[(64 + srow) * BK + scol];
    __bf16* lB0 = &sB[srow * BK + scol];
    __bf16* lB1 = &sB[(64 + srow) * BK + scol];

    f32x4 acc[4][4] = {};

    for (int k0 = 0; k0 < K; k0 += BK) {
        gl_lds_16(gA0 + k0, lA0);
        gl_lds_16(gA1 + k0, lA1);
        gl_lds_16(gB0 + k0, lB0);
        gl_lds_16(gB1 + k0, lB1);
        __syncthreads();   // compiler emits vmcnt(0) drain before s_barrier -> LDS valid

        bf16x8 af[4], bg[4];
#pragma unroll
        for (int mi = 0; mi < 4; ++mi)
            af[mi] = *(const bf16x8*)&sA[(wm * 64 + mi * 16 + lr) * BK + lq * 8];
#pragma unroll
        for (int ni = 0; ni < 4; ++ni)
            bg[ni] = *(const bf16x8*)&sB[(wn * 64 + ni * 16 + lr) * BK + lq * 8];
#pragma unroll
        for (int mi = 0; mi < 4; ++mi)
#pragma unroll
            for (int ni = 0; ni < 4; ++ni)
                acc[mi][ni] = __builtin_amdgcn_mfma_f32_16x16x32_bf16(af[mi], bg[ni], acc[mi][ni], 0, 0, 0);
        __syncthreads();   // protect LDS from next iteration's staging
    }

    // epilogue: C/D layout col=lane&15 (n), row=(lane>>4)*4+reg (m)  [m89-verified]
#pragma unroll
    for (int mi = 0; mi < 4; ++mi) {
#pragma unroll
        for (int ni = 0; ni < 4; ++ni) {
            const int gn = tileN + wn * 64 + ni * 16 + lr;
            const float bv = bias[gn];
#pragma unroll
            for (int r = 0; r < 4; ++r) {
                const int gm = tileM + wm * 64 + mi * 16 + lq * 4 + r;
                C[(size_t)gm * N + gn] = acc[mi][ni][r] + bv;
            }
        }
    }
}

extern "C" void kernel_launch(void* const* d_in, const int* in_sizes, int n_in,
                              void* d_out, int out_size, void* d_ws, size_t ws_size,
                              hipStream_t stream) {
    const float* x    = (const float*)d_in[0];   // (4,2048,4096) fp32
    const float* vals = (const float*)d_in[1];   // (NNZ,) fp32
    const float* bias = (const float*)d_in[2];   // (4096,) fp32
    const int*   idx  = (const int*)d_in[3];     // (NNZ,) flat indices
    float* out = (float*)d_out;                  // (4,2048,4096) fp32

    const int nnz = in_sizes[1];
    const int K = IN_F, N = OUT_F;
    const int M = in_sizes[0] / K;               // 8192

    // workspace layout: [0,64M) W fp32 | [64M,96M) W bf16 | [96M,160M) x bf16
    char* ws = (char*)d_ws;
    float*  Wf = (float*)ws;
    __bf16* Wb = (__bf16*)(ws + (size_t)64 * 1024 * 1024);
    __bf16* Xb = (__bf16*)(ws + (size_t)96 * 1024 * 1024);

    const int wElems = N * K;                    // 16777216
    const int xElems = M * K;                    // 33554432

    zero_f4<<<wElems / 4 / 256, 256, 0, stream>>>((float4*)Wf, wElems / 4);
    scatter_add<<<(nnz + 255) / 256, 256, 0, stream>>>(vals, idx, Wf, nnz);
    cvt_f32_bf16<<<wElems / 4 / 256, 256, 0, stream>>>(Wf, Wb, wElems / 4);
    cvt_f32_bf16<<<xElems / 4 / 256, 256, 0, stream>>>(x, Xb, xElems / 4);

    dim3 grid(N / BN, M / BM);                   // 32 x 64 = 2048 blocks
    gemm_bf16_bt<<<grid, 256, 0, stream>>>(Xb, Wb, bias, out, M, N, K);
}

// Round 2
// 580.952 us; speedup vs baseline: 1.0677x; 1.0677x over previous
//
#include <hip/hip_runtime.h>
#include <hip/hip_bf16.h>
#include <stdint.h>

#define IN_F 4096
#define OUT_F 4096
#define BM 128
#define BN 128
#define BK 32

typedef __attribute__((ext_vector_type(8))) __bf16 bf16x8;
typedef __attribute__((ext_vector_type(4))) __bf16 bf16x4;
typedef __attribute__((ext_vector_type(4))) float f32x4;

__device__ __forceinline__ void gl_lds_16(const void* g, void* l) {
    __builtin_amdgcn_global_load_lds((const __attribute__((address_space(1))) void*)g,
                                     (__attribute__((address_space(3))) void*)l,
                                     16, 0, 0);
}

// ---- sorted-COO coalescing scatter, no atomics ----
// flat_idx is sorted (reference: jnp.sort), so duplicates are adjacent runs.
// The first-occurrence thread sums its run in fp32 and stores bf16 directly.
__global__ void scatter_sorted(const float* __restrict__ vals, const int* __restrict__ idx,
                               __bf16* __restrict__ W, int nnz) {
    int i = blockIdx.x * blockDim.x + threadIdx.x;
    if (i >= nnz) return;
    const int id = idx[i];
    if (i > 0 && idx[i - 1] == id) return;   // not the run owner
    float s = vals[i];
    for (int j = i + 1; j < nnz && idx[j] == id; ++j) s += vals[j];  // runs are tiny
    W[id] = (__bf16)s;
}

// ---- fp32 -> bf16, 4 elems/thread ----
__global__ void cvt_f32_bf16(const float* __restrict__ in, __bf16* __restrict__ out, int n4) {
    int i = blockIdx.x * blockDim.x + threadIdx.x;
    if (i < n4) {
        float4 v = *(const float4*)(in + (size_t)i * 4);
        bf16x4 o;
        o[0] = (__bf16)v.x; o[1] = (__bf16)v.y; o[2] = (__bf16)v.z; o[3] = (__bf16)v.w;
        *(bf16x4*)(out + (size_t)i * 4) = o;
    }
}

// ---- GEMM: C[M,N] = A[M,K] * B[N,K]^T + bias,  bf16 in / fp32 out ----
// m97 structure: 128x128 tile, BK=32, 4 waves 2x2, global_load_lds width=16.
// 1D grid of 2048 blocks with XCD patch swizzle: bid%8 -> patch of 16x16
// tiles, so each XCD's per-k working set (A 128KB + B 128KB) fits its 4MB L2.
__global__ __launch_bounds__(256) void gemm_bf16_bt(
    const __bf16* __restrict__ A, const __bf16* __restrict__ B,
    const float* __restrict__ bias, float* __restrict__ C,
    int M, int N, int K)
{
    __shared__ __align__(16) __bf16 sA[BM * BK];  // 8 KB, unpadded (global_load_lds layout constraint)
    __shared__ __align__(16) __bf16 sB[BN * BK];  // 8 KB

    const int t = threadIdx.x;
    const int wave = t >> 6;
    const int lane = t & 63;
    const int wm = wave >> 1;
    const int wn = wave & 1;
    const int lq = lane >> 4;
    const int lr = lane & 15;

    // XCD patch swizzle: grid (64 M-tiles x 32 N-tiles) -> 8 patches of 16x16
    const int bid  = blockIdx.x;
    const int xcd  = bid & 7;
    const int slot = bid >> 3;                 // 0..255
    const int mt = (xcd >> 1) * 16 + (slot & 15);   // 0..63
    const int nt = (xcd & 1) * 16 + (slot >> 4);    // 0..31
    const int tileM = mt * BM;
    const int tileN = nt * BN;

    // staging: per issue, 256 threads x 16B = 64 rows of 32 bf16; 2 issues/matrix
    const int srow = wave * 16 + (lane >> 2);   // 0..63
    const int scol = (lane & 3) * 8;            // 0,8,16,24

    const __bf16* gA0 = A + (size_t)(tileM + srow) * K + scol;
    const __bf16* gA1 = A + (size_t)(tileM + 64 + srow) * K + scol;
    const __bf16* gB0 = B + (size_t)(tileN + srow) * K + scol;
    const __bf16* gB1 = B + (size_t)(tileN + 64 + srow) * K + scol;
    __bf16* lA0 = &sA[srow * BK + scol];        // == waveBase + lane*16B (DMA constraint)
    __bf16* lA1 = &sA[(64 + srow) * BK + scol];
    __bf16* lB0 = &sB[srow * BK + scol];
    __bf16* lB1 = &sB[(64 + srow) * BK + scol];

    f32x4 acc[4][4] = {};

    for (int k0 = 0; k0 < K; k0 += BK) {
        gl_lds_16(gA0 + k0, lA0);
        gl_lds_16(gA1 + k0, lA1);
        gl_lds_16(gB0 + k0, lB0);
        gl_lds_16(gB1 + k0, lB1);
        __syncthreads();

        bf16x8 af[4], bg[4];
#pragma unroll
        for (int mi = 0; mi < 4; ++mi)
            af[mi] = *(const bf16x8*)&sA[(wm * 64 + mi * 16 + lr) * BK + lq * 8];
#pragma unroll
        for (int ni = 0; ni < 4; ++ni)
            bg[ni] = *(const bf16x8*)&sB[(wn * 64 + ni * 16 + lr) * BK + lq * 8];
#pragma unroll
        for (int mi = 0; mi < 4; ++mi)
#pragma unroll
            for (int ni = 0; ni < 4; ++ni)
                acc[mi][ni] = __builtin_amdgcn_mfma_f32_16x16x32_bf16(af[mi], bg[ni], acc[mi][ni], 0, 0, 0);
        __syncthreads();
    }

    // epilogue: C/D layout col=lane&15 (n), row=(lane>>4)*4+reg (m)  [m89-verified]
#pragma unroll
    for (int mi = 0; mi < 4; ++mi) {
#pragma unroll
        for (int ni = 0; ni < 4; ++ni) {
            const int gn = tileN + wn * 64 + ni * 16 + lr;
            const float bv = bias[gn];
#pragma unroll
            for (int r = 0; r < 4; ++r) {
                const int gm = tileM + wm * 64 + mi * 16 + lq * 4 + r;
                C[(size_t)gm * N + gn] = acc[mi][ni][r] + bv;
            }
        }
    }
}

extern "C" void kernel_launch(void* const* d_in, const int* in_sizes, int n_in,
                              void* d_out, int out_size, void* d_ws, size_t ws_size,
                              hipStream_t stream) {
    const float* x    = (const float*)d_in[0];   // (4,2048,4096) fp32
    const float* vals = (const float*)d_in[1];   // (NNZ,) fp32
    const float* bias = (const float*)d_in[2];   // (4096,) fp32
    const int*   idx  = (const int*)d_in[3];     // (NNZ,) sorted flat indices
    float* out = (float*)d_out;                  // (4,2048,4096) fp32

    const int nnz = in_sizes[1];
    const int K = IN_F, N = OUT_F;
    const int M = in_sizes[0] / K;               // 8192

    // workspace: [0,32M) W bf16 | [32M,96M) x bf16
    char* ws = (char*)d_ws;
    __bf16* Wb = (__bf16*)ws;
    __bf16* Xb = (__bf16*)(ws + (size_t)32 * 1024 * 1024);

    const int wElems = N * K;                    // 16777216
    const int xElems = M * K;                    // 33554432

    hipMemsetAsync(Wb, 0, (size_t)wElems * sizeof(__bf16), stream);   // zero bf16 W (32 MB)
    scatter_sorted<<<(nnz + 255) / 256, 256, 0, stream>>>(vals, idx, Wb, nnz);
    cvt_f32_bf16<<<xElems / 4 / 256, 256, 0, stream>>>(x, Xb, xElems / 4);

    gemm_bf16_bt<<<(M / BM) * (N / BN), 256, 0, stream>>>(Xb, Wb, bias, out, M, N, K);
}

// Round 3
// 578.031 us; speedup vs baseline: 1.0731x; 1.0051x over previous
//
#include <hip/hip_runtime.h>
#include <hip/hip_bf16.h>
#include <stdint.h>

#define IN_F 4096
#define OUT_F 4096
#define BM 128
#define BN 128
#define BK 32

typedef __attribute__((ext_vector_type(8))) __bf16 bf16x8;
typedef __attribute__((ext_vector_type(4))) float f32x4;

__device__ __forceinline__ void gl_lds_16(const void* g, void* l) {
    __builtin_amdgcn_global_load_lds((const __attribute__((address_space(1))) void*)g,
                                     (__attribute__((address_space(3))) void*)l,
                                     16, 0, 0);
}

// ---- fused: x fp32->bf16 (8 elems/thread, 16B stores) + sorted-COO scatter ----
// Blocks [0, cvtBlocks) convert x; blocks [cvtBlocks, ...) do the scatter.
// scatter is latency-bound and rides under the BW-bound cvt in one dispatch.
__global__ void cvt_and_scatter(const float* __restrict__ x, __bf16* __restrict__ Xb, int n8,
                                const float* __restrict__ vals, const int* __restrict__ idx,
                                __bf16* __restrict__ W, int nnz, int cvtBlocks) {
    if ((int)blockIdx.x < cvtBlocks) {
        int i = blockIdx.x * blockDim.x + threadIdx.x;
        if (i < n8) {
            const float4* src = (const float4*)(x + (size_t)i * 8);
            float4 v0 = src[0], v1 = src[1];
            bf16x8 o;
            o[0] = (__bf16)v0.x; o[1] = (__bf16)v0.y; o[2] = (__bf16)v0.z; o[3] = (__bf16)v0.w;
            o[4] = (__bf16)v1.x; o[5] = (__bf16)v1.y; o[6] = (__bf16)v1.z; o[7] = (__bf16)v1.w;
            *(bf16x8*)(Xb + (size_t)i * 8) = o;
        }
    } else {
        // flat_idx is sorted (reference: jnp.sort) -> duplicates are adjacent runs;
        // the run owner sums in fp32 and stores bf16. No atomics.
        int i = (blockIdx.x - cvtBlocks) * blockDim.x + threadIdx.x;
        if (i >= nnz) return;
        const int id = idx[i];
        if (i > 0 && idx[i - 1] == id) return;
        float s = vals[i];
        for (int j = i + 1; j < nnz && idx[j] == id; ++j) s += vals[j];
        W[id] = (__bf16)s;
    }
}

// ---- GEMM: C[M,N] = A[M,K] * B[N,K]^T + bias,  bf16 in / fp32 out ----
// m97 structure: 128x128 tile, BK=32, 4 waves 2x2, global_load_lds width=16.
// XCD patch swizzle (bid%8 -> 16x16-tile patch) — measured neutral, kept.
// LDS bank "conflicts" (4 cyc/b128) are structural: 64 lanes x 16B = 1024B
// needs >=8 bank-passes under any layout; xor-swizzle analysis showed the
// lane->bank distribution is already optimal. Do not re-attempt.
__global__ __launch_bounds__(256) void gemm_bf16_bt(
    const __bf16* __restrict__ A, const __bf16* __restrict__ B,
    const float* __restrict__ bias, float* __restrict__ C,
    int M, int N, int K)
{
    __shared__ __align__(16) __bf16 sA[BM * BK];  // 8 KB, unpadded (global_load_lds layout constraint)
    __shared__ __align__(16) __bf16 sB[BN * BK];  // 8 KB

    const int t = threadIdx.x;
    const int wave = t >> 6;
    const int lane = t & 63;
    const int wm = wave >> 1;
    const int wn = wave & 1;
    const int lq = lane >> 4;
    const int lr = lane & 15;

    const int bid  = blockIdx.x;
    const int xcd  = bid & 7;
    const int slot = bid >> 3;
    const int mt = (xcd >> 1) * 16 + (slot & 15);   // 0..63
    const int nt = (xcd & 1) * 16 + (slot >> 4);    // 0..31
    const int tileM = mt * BM;
    const int tileN = nt * BN;

    const int srow = wave * 16 + (lane >> 2);   // 0..63
    const int scol = (lane & 3) * 8;

    const __bf16* gA0 = A + (size_t)(tileM + srow) * K + scol;
    const __bf16* gA1 = A + (size_t)(tileM + 64 + srow) * K + scol;
    const __bf16* gB0 = B + (size_t)(tileN + srow) * K + scol;
    const __bf16* gB1 = B + (size_t)(tileN + 64 + srow) * K + scol;
    __bf16* lA0 = &sA[srow * BK + scol];        // == waveBase + lane*16B (DMA constraint)
    __bf16* lA1 = &sA[(64 + srow) * BK + scol];
    __bf16* lB0 = &sB[srow * BK + scol];
    __bf16* lB1 = &sB[(64 + srow) * BK + scol];

    f32x4 acc[4][4] = {};

    for (int k0 = 0; k0 < K; k0 += BK) {
        gl_lds_16(gA0 + k0, lA0);
        gl_lds_16(gA1 + k0, lA1);
        gl_lds_16(gB0 + k0, lB0);
        gl_lds_16(gB1 + k0, lB1);
        __syncthreads();

        bf16x8 af[4], bg[4];
#pragma unroll
        for (int mi = 0; mi < 4; ++mi)
            af[mi] = *(const bf16x8*)&sA[(wm * 64 + mi * 16 + lr) * BK + lq * 8];
#pragma unroll
        for (int ni = 0; ni < 4; ++ni)
            bg[ni] = *(const bf16x8*)&sB[(wn * 64 + ni * 16 + lr) * BK + lq * 8];
#pragma unroll
        for (int mi = 0; mi < 4; ++mi)
#pragma unroll
            for (int ni = 0; ni < 4; ++ni)
                acc[mi][ni] = __builtin_amdgcn_mfma_f32_16x16x32_bf16(af[mi], bg[ni], acc[mi][ni], 0, 0, 0);
        __syncthreads();
    }

    // epilogue: C/D layout col=lane&15 (n), row=(lane>>4)*4+reg (m)  [m89-verified]
#pragma unroll
    for (int mi = 0; mi < 4; ++mi) {
#pragma unroll
        for (int ni = 0; ni < 4; ++ni) {
            const int gn = tileN + wn * 64 + ni * 16 + lr;
            const float bv = bias[gn];
#pragma unroll
            for (int r = 0; r < 4; ++r) {
                const int gm = tileM + wm * 64 + mi * 16 + lq * 4 + r;
                C[(size_t)gm * N + gn] = acc[mi][ni][r] + bv;
            }
        }
    }
}

extern "C" void kernel_launch(void* const* d_in, const int* in_sizes, int n_in,
                              void* d_out, int out_size, void* d_ws, size_t ws_size,
                              hipStream_t stream) {
    const float* x    = (const float*)d_in[0];   // (4,2048,4096) fp32
    const float* vals = (const float*)d_in[1];   // (NNZ,) fp32
    const float* bias = (const float*)d_in[2];   // (4096,) fp32
    const int*   idx  = (const int*)d_in[3];     // (NNZ,) sorted flat indices
    float* out = (float*)d_out;                  // (4,2048,4096) fp32

    const int nnz = in_sizes[1];
    const int K = IN_F, N = OUT_F;
    const int M = in_sizes[0] / K;               // 8192

    // workspace: [0,32M) W bf16 | [32M,96M) x bf16
    char* ws = (char*)d_ws;
    __bf16* Wb = (__bf16*)ws;
    __bf16* Xb = (__bf16*)(ws + (size_t)32 * 1024 * 1024);

    const int wElems = N * K;                    // 16777216
    const int xElems = M * K;                    // 33554432
    const int n8 = xElems / 8;                   // 4194304 cvt threads
    const int cvtBlocks = n8 / 256;              // 16384
    const int scatBlocks = (nnz + 255) / 256;    // 6554

    hipMemsetAsync(Wb, 0, (size_t)wElems * sizeof(__bf16), stream);
    cvt_and_scatter<<<cvtBlocks + scatBlocks, 256, 0, stream>>>(
        x, Xb, n8, vals, idx, Wb, nnz, cvtBlocks);

    gemm_bf16_bt<<<(M / BM) * (N / BN), 256, 0, stream>>>(Xb, Wb, bias, out, M, N, K);
}